// Round 1
// baseline (870.653 us; speedup 1.0000x reference)
//
#include <hip/hip_runtime.h>
#include <math.h>

#define TPB 256

#define RMAX_F 2.5f
#define PI_F 3.14159265358979323846f
#define SQRT3_F 1.7320508075688772f
#define INV3_F 0.5773502691896258f
#define INV6_F 0.4082482904638631f
#define PW0_F 0.2041241452319315f      // sqrt(1/24)
#define PW1_F 0.3061862178478972f      // sqrt(3/32)
#define PWSIM_F 0.05590169943749474f   // sqrt(1/320)
#define SILU_C_F 1.676866f             // 1/sqrt(E[silu(N(0,1))^2])
#define RB_F 0.8944271909999159f       // sqrt(2/RMAX)
#define INV_SQRT8_F 0.35355339059327373f

// ---------- helpers ----------

__device__ __forceinline__ unsigned int fkey(float f) {
  unsigned int u = __float_as_uint(f);
  return (u & 0x80000000u) ? ~u : (u | 0x80000000u);
}
__device__ __forceinline__ float fdec(unsigned int u) {
  unsigned int b = (u & 0x80000000u) ? (u ^ 0x80000000u) : ~u;
  return __uint_as_float(b);
}

__device__ __forceinline__ void atomAddF(float* p, float v) {
  unsafeAtomicAdd(p, v);
}

// dot of 16 uniform (scalar-loaded) weights with register h[16]
__device__ __forceinline__ float dot16u(const float* __restrict__ w, const float* __restrict__ h) {
  float a0 = 0.f, a1 = 0.f, a2 = 0.f, a3 = 0.f;
#pragma unroll
  for (int j = 0; j < 16; j += 4) {
    a0 = fmaf(h[j + 0], w[j + 0], a0);
    a1 = fmaf(h[j + 1], w[j + 1], a1);
    a2 = fmaf(h[j + 2], w[j + 2], a2);
    a3 = fmaf(h[j + 3], w[j + 3], a3);
  }
  return (a0 + a1) + (a2 + a3);
}

// geometry + radial basis + basis-net hidden layer (h[16])
__device__ __forceinline__ void compute_h(const float* __restrict__ pos,
                                          const float* __restrict__ W1,
                                          int src, int dst,
                                          float sh1[3], float h[16]) {
  float vx = pos[3 * src + 0] - pos[3 * dst + 0];
  float vy = pos[3 * src + 1] - pos[3 * dst + 1];
  float vz = pos[3 * src + 2] - pos[3 * dst + 2];
  float r2 = fmaf(vx, vx, fmaf(vy, vy, vz * vz)) + 1e-12f;
  float r = sqrtf(r2);
  float inv_r = 1.0f / r;
  sh1[0] = SQRT3_F * vx * inv_r;
  sh1[1] = SQRT3_F * vy * inv_r;
  sh1[2] = SQRT3_F * vz * inv_r;
  float f = (r < RMAX_F) ? (RB_F * inv_r) : 0.0f;
  float t0 = (PI_F / RMAX_F) * r;
  float s1, c1;
  __sincosf(t0, &s1, &c1);
  float c2 = 2.0f * c1;
  float sm = 0.0f, sc = s1;   // sin(0), sin(t0)
  float acc[16];
#pragma unroll
  for (int j = 0; j < 16; ++j) acc[j] = 0.0f;
#pragma unroll 1
  for (int n = 0; n < 32; ++n) {
    float rb = f * sc;                 // sqrt(32) of rb and 1/sqrt(32) of W1 cancel
    const float* wrow = W1 + n * 16;
#pragma unroll
    for (int j = 0; j < 16; ++j) acc[j] = fmaf(rb, wrow[j], acc[j]);
    float nx = fmaf(c2, sc, -sm);      // sin((n+2)t) = 2cos(t)sin((n+1)t) - sin(nt)
    sm = sc; sc = nx;
  }
#pragma unroll
  for (int j = 0; j < 16; ++j) {
    float v = acc[j];
    float sg = 1.0f / (1.0f + __expf(-v));
    h[j] = SILU_C_F * v * sg;
  }
}

// ---------- kernels ----------

// transpose W2 (scale folded) + combined q/sim matrices
__global__ void k_prep(const float* __restrict__ wk2, const float* __restrict__ wv2,
                       const float* __restrict__ wq0, const float* __restrict__ wq1,
                       const float* __restrict__ ws0, const float* __restrict__ ws1,
                       float* __restrict__ W2Tk, float* __restrict__ W2Tv,
                       float* __restrict__ C0, float* __restrict__ C1) {
  int i = blockIdx.x * blockDim.x + threadIdx.x;
  if (i < 10240) {
    int o = i >> 4, j = i & 15;
    W2Tk[i] = wk2[j * 640 + o] * 0.25f;
  } else if (i < 20480) {
    int k = i - 10240;
    int o = k >> 4, j = k & 15;
    W2Tv[k] = wv2[j * 640 + o] * 0.25f;
  } else if (i < 20736) {
    int k = i - 20480;
    int t = k >> 4, v = k & 15;
    float a = 0.f;
#pragma unroll
    for (int u = 0; u < 16; ++u) a = fmaf(wq0[t * 16 + u] * 0.25f, ws0[u * 16 + v], a);
    C0[k] = a;
  } else if (i < 20800) {
    int k = i - 20736;
    int t = k >> 3, v = k & 7;
    float a = 0.f;
#pragma unroll
    for (int u = 0; u < 8; ++u) a = fmaf(wq1[t * 8 + u] * INV_SQRT8_F, ws1[u * 8 + v], a);
    C1[k] = a;
  }
}

// per-node: qs0 = x0 @ C0, qs1[v][i] = sum_u x1[u][i] C1[u][v]
__global__ void k_node(const float* __restrict__ x, const float* __restrict__ C0,
                       const float* __restrict__ C1, float* __restrict__ qs0g,
                       float* __restrict__ qs1g, int N) {
  int n = blockIdx.x * blockDim.x + threadIdx.x;
  if (n >= N) return;
  float xr[40];
  const float4* p = reinterpret_cast<const float4*>(x + (size_t)n * 40);
#pragma unroll
  for (int q = 0; q < 10; ++q) {
    float4 v = p[q];
    xr[q * 4 + 0] = v.x; xr[q * 4 + 1] = v.y; xr[q * 4 + 2] = v.z; xr[q * 4 + 3] = v.w;
  }
  float o0[16];
#pragma unroll
  for (int v = 0; v < 16; ++v) o0[v] = 0.f;
#pragma unroll
  for (int t = 0; t < 16; ++t) {
    float xt = xr[t];
    const float* c = C0 + t * 16;
#pragma unroll
    for (int v = 0; v < 16; ++v) o0[v] = fmaf(xt, c[v], o0[v]);
  }
  float4* q0p = reinterpret_cast<float4*>(qs0g + (size_t)n * 16);
#pragma unroll
  for (int q = 0; q < 4; ++q)
    q0p[q] = make_float4(o0[q * 4], o0[q * 4 + 1], o0[q * 4 + 2], o0[q * 4 + 3]);

  float o1[24];
#pragma unroll
  for (int v = 0; v < 24; ++v) o1[v] = 0.f;
#pragma unroll
  for (int u = 0; u < 8; ++u) {
    const float* c = C1 + u * 8;
    float xa = xr[16 + u * 3 + 0], xb = xr[16 + u * 3 + 1], xc = xr[16 + u * 3 + 2];
#pragma unroll
    for (int v = 0; v < 8; ++v) {
      float cv = c[v];
      o1[v * 3 + 0] = fmaf(xa, cv, o1[v * 3 + 0]);
      o1[v * 3 + 1] = fmaf(xb, cv, o1[v * 3 + 1]);
      o1[v * 3 + 2] = fmaf(xc, cv, o1[v * 3 + 2]);
    }
  }
  float4* q1p = reinterpret_cast<float4*>(qs1g + (size_t)n * 24);
#pragma unroll
  for (int q = 0; q < 6; ++q)
    q1p[q] = make_float4(o1[q * 4], o1[q * 4 + 1], o1[q * 4 + 2], o1[q * 4 + 3]);
}

// per-edge: similarity s (key net folded into 5 scalar accumulators), atomic segment max
__global__ __launch_bounds__(TPB) void k_edge_key(
    const float* __restrict__ x, const float* __restrict__ pos,
    const int* __restrict__ esrc, const int* __restrict__ edst,
    const float* __restrict__ W1, const float* __restrict__ W2T,
    const float* __restrict__ qs0g, const float* __restrict__ qs1g,
    float* __restrict__ s_out, unsigned int* __restrict__ smax_enc, int E) {
  __shared__ float xs[TPB * 41];
  int e = blockIdx.x * TPB + threadIdx.x;
  if (e >= E) return;
  int src = esrc[e], dst = edst[e];

  float* myx = &xs[threadIdx.x * 41];
  const float4* xrow = reinterpret_cast<const float4*>(x + (size_t)src * 40);
#pragma unroll
  for (int q = 0; q < 10; ++q) {
    float4 v = xrow[q];
    myx[q * 4 + 0] = v.x; myx[q * 4 + 1] = v.y; myx[q * 4 + 2] = v.z; myx[q * 4 + 3] = v.w;
  }

  float sh1[3], h[16];
  compute_h(pos, W1, src, dst, sh1, h);

  float qs0[16];
  {
    const float4* p = reinterpret_cast<const float4*>(qs0g + (size_t)dst * 16);
#pragma unroll
    for (int q = 0; q < 4; ++q) {
      float4 v = p[q];
      qs0[q * 4 + 0] = v.x; qs0[q * 4 + 1] = v.y; qs0[q * 4 + 2] = v.z; qs0[q * 4 + 3] = v.w;
    }
  }
  float qs1[24];
  {
    const float4* p = reinterpret_cast<const float4*>(qs1g + (size_t)dst * 24);
#pragma unroll
    for (int q = 0; q < 6; ++q) {
      float4 v = p[q];
      qs1[q * 4 + 0] = v.x; qs1[q * 4 + 1] = v.y; qs1[q * 4 + 2] = v.z; qs1[q * 4 + 3] = v.w;
    }
  }
  float qsh[8];
#pragma unroll
  for (int w = 0; w < 8; ++w)
    qsh[w] = qs1[w * 3] * sh1[0] + qs1[w * 3 + 1] * sh1[1] + qs1[w * 3 + 2] * sh1[2];

  float S0a = 0.f, S0b = 0.f, S1a = 0.f, S1b = 0.f, S1c = 0.f;

  // w0 block: o = u*16+w -> S0a += wk * x0[u] * qs0[w]
#pragma unroll 1
  for (int u = 0; u < 16; ++u) {
    const float* base = W2T + (u * 16) * 16;
    float accu = 0.f;
#pragma unroll
    for (int w = 0; w < 16; ++w) accu = fmaf(dot16u(base + w * 16, h), qs0[w], accu);
    S0a = fmaf(accu, myx[u], S0a);
  }
  // w1 block: o = 256 + u*8 + w -> S1a += wk * x0[u] * qsh[w]
#pragma unroll 1
  for (int u = 0; u < 16; ++u) {
    const float* base = W2T + (256 + u * 8) * 16;
    float accu = 0.f;
#pragma unroll
    for (int w = 0; w < 8; ++w) accu = fmaf(dot16u(base + w * 16, h), qsh[w], accu);
    S1a = fmaf(accu, myx[u], S1a);
  }
  // w2 block: o = 384 + u*8 + w -> S1b += wk * (x1[u] . qs1[w])
#pragma unroll 1
  for (int u = 0; u < 8; ++u) {
    const float* base = W2T + (384 + u * 8) * 16;
    float x1a = myx[16 + u * 3 + 0], x1b = myx[16 + u * 3 + 1], x1c = myx[16 + u * 3 + 2];
    float accu = 0.f;
#pragma unroll
    for (int w = 0; w < 8; ++w) {
      float t = qs1[w * 3] * x1a + qs1[w * 3 + 1] * x1b + qs1[w * 3 + 2] * x1c;
      accu = fmaf(dot16u(base + w * 16, h), t, accu);
    }
    S1b += accu;
  }
  // w3 block: o = 448 + u*16 + w -> S0b += wk * dot[u] * qs0[w]
#pragma unroll 1
  for (int u = 0; u < 8; ++u) {
    const float* base = W2T + (448 + u * 16) * 16;
    float x1a = myx[16 + u * 3 + 0], x1b = myx[16 + u * 3 + 1], x1c = myx[16 + u * 3 + 2];
    float du = x1a * sh1[0] + x1b * sh1[1] + x1c * sh1[2];
    float accu = 0.f;
#pragma unroll
    for (int w = 0; w < 16; ++w) accu = fmaf(dot16u(base + w * 16, h), qs0[w], accu);
    S0b = fmaf(accu, du, S0b);
  }
  // w4 block: o = 576 + u*8 + w -> S1c += wk * (crx[u] . qs1[w])
#pragma unroll 1
  for (int u = 0; u < 8; ++u) {
    const float* base = W2T + (576 + u * 8) * 16;
    float x1a = myx[16 + u * 3 + 0], x1b = myx[16 + u * 3 + 1], x1c = myx[16 + u * 3 + 2];
    float cx = x1b * sh1[2] - x1c * sh1[1];
    float cy = x1c * sh1[0] - x1a * sh1[2];
    float cz = x1a * sh1[1] - x1b * sh1[0];
    float accu = 0.f;
#pragma unroll
    for (int w = 0; w < 8; ++w) {
      float t = qs1[w * 3] * cx + qs1[w * 3 + 1] * cy + qs1[w * 3 + 2] * cz;
      accu = fmaf(dot16u(base + w * 16, h), t, accu);
    }
    S1c += accu;
  }

  float s = PWSIM_F * (PW0_F * (S0a + INV3_F * S0b) +
                       (INV3_F * PW1_F) * (INV3_F * S1a + INV3_F * S1b + INV6_F * S1c));
  s_out[e] = s;
  atomicMax(&smax_enc[dst], fkey(s));
}

// per-edge: softmax denominator
__global__ void k_denom(const float* __restrict__ s_in, const int* __restrict__ edst,
                        const unsigned int* __restrict__ smax_enc,
                        float* __restrict__ denom, int E) {
  int e = blockIdx.x * blockDim.x + threadIdx.x;
  if (e >= E) return;
  int dst = edst[e];
  float mx = fdec(smax_enc[dst]);
  atomAddF(&denom[dst], __expf(s_in[e] - mx));
}

// per-edge: value net + attention-weighted scatter
__global__ __launch_bounds__(TPB) void k_edge_val(
    const float* __restrict__ x, const float* __restrict__ pos,
    const int* __restrict__ esrc, const int* __restrict__ edst,
    const float* __restrict__ W1, const float* __restrict__ W2T,
    const float* __restrict__ s_in, const unsigned int* __restrict__ smax_enc,
    const float* __restrict__ denom, float* __restrict__ out, int E) {
  __shared__ float xs[TPB * 41];
  int e = blockIdx.x * TPB + threadIdx.x;
  if (e >= E) return;
  int src = esrc[e], dst = edst[e];

  float* myx = &xs[threadIdx.x * 41];
  const float4* xrow = reinterpret_cast<const float4*>(x + (size_t)src * 40);
#pragma unroll
  for (int q = 0; q < 10; ++q) {
    float4 v = xrow[q];
    myx[q * 4 + 0] = v.x; myx[q * 4 + 1] = v.y; myx[q * 4 + 2] = v.z; myx[q * 4 + 3] = v.w;
  }

  float sh1[3], h[16];
  compute_h(pos, W1, src, dst, sh1, h);

  float v0[16];
#pragma unroll
  for (int w = 0; w < 16; ++w) v0[w] = 0.f;
  float v1[24];
#pragma unroll
  for (int w = 0; w < 24; ++w) v1[w] = 0.f;

  // w0 block
#pragma unroll 1
  for (int u = 0; u < 16; ++u) {
    const float* base = W2T + (u * 16) * 16;
    float xu = myx[u];
#pragma unroll
    for (int w = 0; w < 16; ++w) v0[w] = fmaf(dot16u(base + w * 16, h), xu, v0[w]);
  }
  // w1 block
  float aw[8];
#pragma unroll
  for (int w = 0; w < 8; ++w) aw[w] = 0.f;
#pragma unroll 1
  for (int u = 0; u < 16; ++u) {
    const float* base = W2T + (256 + u * 8) * 16;
    float xu = myx[u];
#pragma unroll
    for (int w = 0; w < 8; ++w) aw[w] = fmaf(dot16u(base + w * 16, h), xu, aw[w]);
  }
#pragma unroll
  for (int w = 0; w < 8; ++w) {
    float t = INV3_F * aw[w];
    v1[w * 3 + 0] = fmaf(t, sh1[0], v1[w * 3 + 0]);
    v1[w * 3 + 1] = fmaf(t, sh1[1], v1[w * 3 + 1]);
    v1[w * 3 + 2] = fmaf(t, sh1[2], v1[w * 3 + 2]);
  }
  // w2 block
#pragma unroll 1
  for (int u = 0; u < 8; ++u) {
    const float* base = W2T + (384 + u * 8) * 16;
    float a0 = INV3_F * myx[16 + u * 3 + 0];
    float a1 = INV3_F * myx[16 + u * 3 + 1];
    float a2 = INV3_F * myx[16 + u * 3 + 2];
#pragma unroll
    for (int w = 0; w < 8; ++w) {
      float wk = dot16u(base + w * 16, h);
      v1[w * 3 + 0] = fmaf(wk, a0, v1[w * 3 + 0]);
      v1[w * 3 + 1] = fmaf(wk, a1, v1[w * 3 + 1]);
      v1[w * 3 + 2] = fmaf(wk, a2, v1[w * 3 + 2]);
    }
  }
  // w3 block
#pragma unroll 1
  for (int u = 0; u < 8; ++u) {
    const float* base = W2T + (448 + u * 16) * 16;
    float x1a = myx[16 + u * 3 + 0], x1b = myx[16 + u * 3 + 1], x1c = myx[16 + u * 3 + 2];
    float du = INV3_F * (x1a * sh1[0] + x1b * sh1[1] + x1c * sh1[2]);
#pragma unroll
    for (int w = 0; w < 16; ++w) v0[w] = fmaf(dot16u(base + w * 16, h), du, v0[w]);
  }
  // w4 block
#pragma unroll 1
  for (int u = 0; u < 8; ++u) {
    const float* base = W2T + (576 + u * 8) * 16;
    float x1a = myx[16 + u * 3 + 0], x1b = myx[16 + u * 3 + 1], x1c = myx[16 + u * 3 + 2];
    float cx = INV6_F * (x1b * sh1[2] - x1c * sh1[1]);
    float cy = INV6_F * (x1c * sh1[0] - x1a * sh1[2]);
    float cz = INV6_F * (x1a * sh1[1] - x1b * sh1[0]);
#pragma unroll
    for (int w = 0; w < 8; ++w) {
      float wk = dot16u(base + w * 16, h);
      v1[w * 3 + 0] = fmaf(wk, cx, v1[w * 3 + 0]);
      v1[w * 3 + 1] = fmaf(wk, cy, v1[w * 3 + 1]);
      v1[w * 3 + 2] = fmaf(wk, cz, v1[w * 3 + 2]);
    }
  }

  float mx = fdec(smax_enc[dst]);
  float ex = __expf(s_in[e] - mx);
  float coef = sqrtf(__fdividef(ex, denom[dst]));

  float* op = out + (size_t)dst * 40;
#pragma unroll
  for (int w = 0; w < 16; ++w) atomAddF(op + w, coef * PW0_F * v0[w]);
#pragma unroll
  for (int w = 0; w < 24; ++w) atomAddF(op + 16 + w, coef * PW1_F * v1[w]);
}

// ---------- host launcher ----------

extern "C" void kernel_launch(void* const* d_in, const int* in_sizes, int n_in,
                              void* d_out, int out_size, void* d_ws, size_t ws_size,
                              hipStream_t stream) {
  const float* x   = (const float*)d_in[0];
  const float* pos = (const float*)d_in[1];
  const int* esrc  = (const int*)d_in[2];
  const int* edst  = (const int*)d_in[3];
  const float* wk1 = (const float*)d_in[4];
  const float* wk2 = (const float*)d_in[5];
  const float* wv1 = (const float*)d_in[6];
  const float* wv2 = (const float*)d_in[7];
  const float* wq0 = (const float*)d_in[8];
  const float* wq1 = (const float*)d_in[9];
  const float* ws0 = (const float*)d_in[10];
  const float* ws1 = (const float*)d_in[11];

  int E = in_sizes[2];
  int N = in_sizes[0] / 40;

  float* ws = (float*)d_ws;
  float* W2Tk = ws;                        // 10240
  float* W2Tv = ws + 10240;                // 10240
  float* C0   = ws + 20480;                // 256
  float* C1   = ws + 20736;                // 64
  float* qs0g = ws + 20800;                // N*16
  float* qs1g = qs0g + (size_t)N * 16;     // N*24
  float* s_ws = qs1g + (size_t)N * 24;     // E
  unsigned int* smax_enc = (unsigned int*)(s_ws + (size_t)E);  // N
  float* denom = (float*)(smax_enc + (size_t)N);               // N

  hipMemsetAsync(d_out, 0, sizeof(float) * (size_t)out_size, stream);
  hipMemsetAsync(smax_enc, 0, sizeof(unsigned int) * (size_t)N, stream);
  hipMemsetAsync(denom, 0, sizeof(float) * (size_t)N, stream);

  k_prep<<<(20800 + 255) / 256, 256, 0, stream>>>(wk2, wv2, wq0, wq1, ws0, ws1,
                                                  W2Tk, W2Tv, C0, C1);
  k_node<<<(N + 255) / 256, 256, 0, stream>>>(x, C0, C1, qs0g, qs1g, N);
  k_edge_key<<<(E + TPB - 1) / TPB, TPB, 0, stream>>>(x, pos, esrc, edst, wk1, W2Tk,
                                                      qs0g, qs1g, s_ws, smax_enc, E);
  k_denom<<<(E + 255) / 256, 256, 0, stream>>>(s_ws, edst, smax_enc, denom, E);
  k_edge_val<<<(E + TPB - 1) / TPB, TPB, 0, stream>>>(x, pos, esrc, edst, wv1, W2Tv,
                                                      s_ws, smax_enc, denom,
                                                      (float*)d_out, E);
}

// Round 2
// 543.767 us; speedup vs baseline: 1.6012x; 1.6012x over previous
//
#include <hip/hip_runtime.h>
#include <math.h>

#define TPB 256

#define RMAX_F 2.5f
#define PI_F 3.14159265358979323846f
#define SQRT3_F 1.7320508075688772f
#define INV3_F 0.5773502691896258f
#define INV6_F 0.4082482904638631f
#define PW0_F 0.2041241452319315f      // sqrt(1/24)
#define PW1_F 0.3061862178478972f      // sqrt(3/32)
#define PWSIM_F 0.05590169943749474f   // sqrt(1/320)
#define SILU_C_F 1.676866f             // 1/sqrt(E[silu(N(0,1))^2])
#define RB_F 0.8944271909999159f       // sqrt(2/RMAX)
#define INV_SQRT8_F 0.35355339059327373f

// ---------- helpers ----------

__device__ __forceinline__ unsigned int fkey(float f) {
  unsigned int u = __float_as_uint(f);
  return (u & 0x80000000u) ? ~u : (u | 0x80000000u);
}
__device__ __forceinline__ float fdec(unsigned int u) {
  unsigned int b = (u & 0x80000000u) ? (u ^ 0x80000000u) : ~u;
  return __uint_as_float(b);
}

__device__ __forceinline__ void atomAddF(float* p, float v) {
  unsafeAtomicAdd(p, v);
}

// dot of 16 uniform (scalar-loaded) weights with register h[16]
__device__ __forceinline__ float dot16u(const float* __restrict__ w, const float* __restrict__ h) {
  float a0 = 0.f, a1 = 0.f, a2 = 0.f, a3 = 0.f;
#pragma unroll
  for (int j = 0; j < 16; j += 4) {
    a0 = fmaf(h[j + 0], w[j + 0], a0);
    a1 = fmaf(h[j + 1], w[j + 1], a1);
    a2 = fmaf(h[j + 2], w[j + 2], a2);
    a3 = fmaf(h[j + 3], w[j + 3], a3);
  }
  return (a0 + a1) + (a2 + a3);
}

// geometry + radial basis + ONE basis-net hidden layer
__device__ __forceinline__ void compute_h(const float* __restrict__ pos,
                                          const float* __restrict__ W1,
                                          int src, int dst,
                                          float sh1[3], float h[16]) {
  float vx = pos[3 * src + 0] - pos[3 * dst + 0];
  float vy = pos[3 * src + 1] - pos[3 * dst + 1];
  float vz = pos[3 * src + 2] - pos[3 * dst + 2];
  float r2 = fmaf(vx, vx, fmaf(vy, vy, vz * vz)) + 1e-12f;
  float r = sqrtf(r2);
  float inv_r = 1.0f / r;
  sh1[0] = SQRT3_F * vx * inv_r;
  sh1[1] = SQRT3_F * vy * inv_r;
  sh1[2] = SQRT3_F * vz * inv_r;
  float f = (r < RMAX_F) ? (RB_F * inv_r) : 0.0f;
  float t0 = (PI_F / RMAX_F) * r;
  float s1, c1;
  __sincosf(t0, &s1, &c1);
  float c2 = 2.0f * c1;
  float sm = 0.0f, sc = s1;
  float acc[16];
#pragma unroll
  for (int j = 0; j < 16; ++j) acc[j] = 0.0f;
#pragma unroll 1
  for (int n = 0; n < 32; ++n) {
    float rb = f * sc;
    const float* wrow = W1 + n * 16;
#pragma unroll
    for (int j = 0; j < 16; ++j) acc[j] = fmaf(rb, wrow[j], acc[j]);
    float nx = fmaf(c2, sc, -sm);
    sm = sc; sc = nx;
  }
#pragma unroll
  for (int j = 0; j < 16; ++j) {
    float v = acc[j];
    float sg = 1.0f / (1.0f + __expf(-v));
    h[j] = SILU_C_F * v * sg;
  }
}

// geometry + radial basis + BOTH basis-net hidden layers (shared sin chain)
__device__ __forceinline__ void compute_h2(const float* __restrict__ pos,
                                           const float* __restrict__ W1k,
                                           const float* __restrict__ W1v,
                                           int src, int dst,
                                           float sh1[3], float hk[16], float hv[16]) {
  float vx = pos[3 * src + 0] - pos[3 * dst + 0];
  float vy = pos[3 * src + 1] - pos[3 * dst + 1];
  float vz = pos[3 * src + 2] - pos[3 * dst + 2];
  float r2 = fmaf(vx, vx, fmaf(vy, vy, vz * vz)) + 1e-12f;
  float r = sqrtf(r2);
  float inv_r = 1.0f / r;
  sh1[0] = SQRT3_F * vx * inv_r;
  sh1[1] = SQRT3_F * vy * inv_r;
  sh1[2] = SQRT3_F * vz * inv_r;
  float f = (r < RMAX_F) ? (RB_F * inv_r) : 0.0f;
  float t0 = (PI_F / RMAX_F) * r;
  float s1, c1;
  __sincosf(t0, &s1, &c1);
  float c2 = 2.0f * c1;
  float sm = 0.0f, sc = s1;
  float ak[16], av[16];
#pragma unroll
  for (int j = 0; j < 16; ++j) { ak[j] = 0.0f; av[j] = 0.0f; }
#pragma unroll 1
  for (int n = 0; n < 32; ++n) {
    float rb = f * sc;
    const float* wk = W1k + n * 16;
    const float* wv = W1v + n * 16;
#pragma unroll
    for (int j = 0; j < 16; ++j) ak[j] = fmaf(rb, wk[j], ak[j]);
#pragma unroll
    for (int j = 0; j < 16; ++j) av[j] = fmaf(rb, wv[j], av[j]);
    float nx = fmaf(c2, sc, -sm);
    sm = sc; sc = nx;
  }
#pragma unroll
  for (int j = 0; j < 16; ++j) {
    float v = ak[j];
    hk[j] = SILU_C_F * v * (1.0f / (1.0f + __expf(-v)));
    float w = av[j];
    hv[j] = SILU_C_F * w * (1.0f / (1.0f + __expf(-w)));
  }
}

// ---------- prep kernels ----------

__global__ void k_prep(const float* __restrict__ wk2, const float* __restrict__ wv2,
                       const float* __restrict__ wq0, const float* __restrict__ wq1,
                       const float* __restrict__ ws0, const float* __restrict__ ws1,
                       float* __restrict__ W2Tk, float* __restrict__ W2Tv,
                       float* __restrict__ C0, float* __restrict__ C1) {
  int i = blockIdx.x * blockDim.x + threadIdx.x;
  if (i < 10240) {
    int o = i >> 4, j = i & 15;
    W2Tk[i] = wk2[j * 640 + o] * 0.25f;
  } else if (i < 20480) {
    int k = i - 10240;
    int o = k >> 4, j = k & 15;
    W2Tv[k] = wv2[j * 640 + o] * 0.25f;
  } else if (i < 20736) {
    int k = i - 20480;
    int t = k >> 4, v = k & 15;
    float a = 0.f;
#pragma unroll
    for (int u = 0; u < 16; ++u) a = fmaf(wq0[t * 16 + u] * 0.25f, ws0[u * 16 + v], a);
    C0[k] = a;
  } else if (i < 20800) {
    int k = i - 20736;
    int t = k >> 3, v = k & 7;
    float a = 0.f;
#pragma unroll
    for (int u = 0; u < 8; ++u) a = fmaf(wq1[t * 8 + u] * INV_SQRT8_F, ws1[u * 8 + v], a);
    C1[k] = a;
  }
}

__global__ void k_node(const float* __restrict__ x, const float* __restrict__ C0,
                       const float* __restrict__ C1, float* __restrict__ qs0g,
                       float* __restrict__ qs1g, int N) {
  int n = blockIdx.x * blockDim.x + threadIdx.x;
  if (n >= N) return;
  float xr[40];
  const float4* p = reinterpret_cast<const float4*>(x + (size_t)n * 40);
#pragma unroll
  for (int q = 0; q < 10; ++q) {
    float4 v = p[q];
    xr[q * 4 + 0] = v.x; xr[q * 4 + 1] = v.y; xr[q * 4 + 2] = v.z; xr[q * 4 + 3] = v.w;
  }
  float o0[16];
#pragma unroll
  for (int v = 0; v < 16; ++v) o0[v] = 0.f;
#pragma unroll
  for (int t = 0; t < 16; ++t) {
    float xt = xr[t];
    const float* c = C0 + t * 16;
#pragma unroll
    for (int v = 0; v < 16; ++v) o0[v] = fmaf(xt, c[v], o0[v]);
  }
  float4* q0p = reinterpret_cast<float4*>(qs0g + (size_t)n * 16);
#pragma unroll
  for (int q = 0; q < 4; ++q)
    q0p[q] = make_float4(o0[q * 4], o0[q * 4 + 1], o0[q * 4 + 2], o0[q * 4 + 3]);

  float o1[24];
#pragma unroll
  for (int v = 0; v < 24; ++v) o1[v] = 0.f;
#pragma unroll
  for (int u = 0; u < 8; ++u) {
    const float* c = C1 + u * 8;
    float xa = xr[16 + u * 3 + 0], xb = xr[16 + u * 3 + 1], xc = xr[16 + u * 3 + 2];
#pragma unroll
    for (int v = 0; v < 8; ++v) {
      float cv = c[v];
      o1[v * 3 + 0] = fmaf(xa, cv, o1[v * 3 + 0]);
      o1[v * 3 + 1] = fmaf(xb, cv, o1[v * 3 + 1]);
      o1[v * 3 + 2] = fmaf(xc, cv, o1[v * 3 + 2]);
    }
  }
  float4* q1p = reinterpret_cast<float4*>(qs1g + (size_t)n * 24);
#pragma unroll
  for (int q = 0; q < 6; ++q)
    q1p[q] = make_float4(o1[q * 4], o1[q * 4 + 1], o1[q * 4 + 2], o1[q * 4 + 3]);
}

// ---------- CSR build ----------

__global__ void k_hist(const int* __restrict__ edst, int* __restrict__ cnt, int E) {
  int e = blockIdx.x * blockDim.x + threadIdx.x;
  if (e < E) atomicAdd(&cnt[edst[e]], 1);
}

__global__ __launch_bounds__(1024) void k_scan(const int* __restrict__ cnt,
                                               int* __restrict__ off,
                                               int* __restrict__ cursor, int N) {
  __shared__ int ls[1024];
  int tid = threadIdx.x;
  int per = (N + 1023) >> 10;
  int base = tid * per;
  int sum = 0;
  for (int j = 0; j < per; ++j) {
    int idx = base + j;
    if (idx < N) sum += cnt[idx];
  }
  ls[tid] = sum;
  __syncthreads();
  for (int d = 1; d < 1024; d <<= 1) {
    int v = (tid >= d) ? ls[tid - d] : 0;
    __syncthreads();
    ls[tid] += v;
    __syncthreads();
  }
  int run = ls[tid] - sum;
  for (int j = 0; j < per; ++j) {
    int idx = base + j;
    if (idx < N) {
      off[idx] = run;
      cursor[idx] = run;
      run += cnt[idx];
    }
  }
  if (tid == 1023) off[N] = run;
}

__global__ void k_place(const int* __restrict__ edst, int* __restrict__ cursor,
                        int* __restrict__ perm, int E) {
  int e = blockIdx.x * blockDim.x + threadIdx.x;
  if (e < E) {
    int p = atomicAdd(&cursor[edst[e]], 1);
    perm[p] = e;
  }
}

// ---------- fused edge kernel (key + value nets, no atomics) ----------

__global__ __launch_bounds__(TPB) void k_edge_fused(
    const float* __restrict__ x, const float* __restrict__ pos,
    const int* __restrict__ esrc, const int* __restrict__ edst,
    const int* __restrict__ perm,
    const float* __restrict__ W1k, const float* __restrict__ W2Tk,
    const float* __restrict__ W1v, const float* __restrict__ W2Tv,
    const float* __restrict__ qs0g, const float* __restrict__ qs1g,
    float* __restrict__ s_out, float* __restrict__ staging, int E) {
  __shared__ float xs[TPB * 41];
  int p = blockIdx.x * TPB + threadIdx.x;
  if (p >= E) return;
  int e = perm[p];
  int src = esrc[e], dst = edst[e];

  float* myx = &xs[threadIdx.x * 41];
  const float4* xrow = reinterpret_cast<const float4*>(x + (size_t)src * 40);
#pragma unroll
  for (int q = 0; q < 10; ++q) {
    float4 v = xrow[q];
    myx[q * 4 + 0] = v.x; myx[q * 4 + 1] = v.y; myx[q * 4 + 2] = v.z; myx[q * 4 + 3] = v.w;
  }

  float sh1[3], hk[16], hv[16];
  compute_h2(pos, W1k, W1v, src, dst, sh1, hk, hv);

  // ------- key phase: similarity s -------
  {
    float qs0[16];
    {
      const float4* qp = reinterpret_cast<const float4*>(qs0g + (size_t)dst * 16);
#pragma unroll
      for (int q = 0; q < 4; ++q) {
        float4 v = qp[q];
        qs0[q * 4 + 0] = v.x; qs0[q * 4 + 1] = v.y; qs0[q * 4 + 2] = v.z; qs0[q * 4 + 3] = v.w;
      }
    }
    float qs1[24];
    {
      const float4* qp = reinterpret_cast<const float4*>(qs1g + (size_t)dst * 24);
#pragma unroll
      for (int q = 0; q < 6; ++q) {
        float4 v = qp[q];
        qs1[q * 4 + 0] = v.x; qs1[q * 4 + 1] = v.y; qs1[q * 4 + 2] = v.z; qs1[q * 4 + 3] = v.w;
      }
    }
    float qsh[8];
#pragma unroll
    for (int w = 0; w < 8; ++w)
      qsh[w] = qs1[w * 3] * sh1[0] + qs1[w * 3 + 1] * sh1[1] + qs1[w * 3 + 2] * sh1[2];

    float S0a = 0.f, S0b = 0.f, S1a = 0.f, S1b = 0.f, S1c = 0.f;

#pragma unroll 1
    for (int u = 0; u < 16; ++u) {
      const float* base = W2Tk + (u * 16) * 16;
      float accu = 0.f;
#pragma unroll
      for (int w = 0; w < 16; ++w) accu = fmaf(dot16u(base + w * 16, hk), qs0[w], accu);
      S0a = fmaf(accu, myx[u], S0a);
    }
#pragma unroll 1
    for (int u = 0; u < 16; ++u) {
      const float* base = W2Tk + (256 + u * 8) * 16;
      float accu = 0.f;
#pragma unroll
      for (int w = 0; w < 8; ++w) accu = fmaf(dot16u(base + w * 16, hk), qsh[w], accu);
      S1a = fmaf(accu, myx[u], S1a);
    }
#pragma unroll 1
    for (int u = 0; u < 8; ++u) {
      const float* base = W2Tk + (384 + u * 8) * 16;
      float x1a = myx[16 + u * 3 + 0], x1b = myx[16 + u * 3 + 1], x1c = myx[16 + u * 3 + 2];
      float accu = 0.f;
#pragma unroll
      for (int w = 0; w < 8; ++w) {
        float t = qs1[w * 3] * x1a + qs1[w * 3 + 1] * x1b + qs1[w * 3 + 2] * x1c;
        accu = fmaf(dot16u(base + w * 16, hk), t, accu);
      }
      S1b += accu;
    }
#pragma unroll 1
    for (int u = 0; u < 8; ++u) {
      const float* base = W2Tk + (448 + u * 16) * 16;
      float x1a = myx[16 + u * 3 + 0], x1b = myx[16 + u * 3 + 1], x1c = myx[16 + u * 3 + 2];
      float du = x1a * sh1[0] + x1b * sh1[1] + x1c * sh1[2];
      float accu = 0.f;
#pragma unroll
      for (int w = 0; w < 16; ++w) accu = fmaf(dot16u(base + w * 16, hk), qs0[w], accu);
      S0b = fmaf(accu, du, S0b);
    }
#pragma unroll 1
    for (int u = 0; u < 8; ++u) {
      const float* base = W2Tk + (576 + u * 8) * 16;
      float x1a = myx[16 + u * 3 + 0], x1b = myx[16 + u * 3 + 1], x1c = myx[16 + u * 3 + 2];
      float cx = x1b * sh1[2] - x1c * sh1[1];
      float cy = x1c * sh1[0] - x1a * sh1[2];
      float cz = x1a * sh1[1] - x1b * sh1[0];
      float accu = 0.f;
#pragma unroll
      for (int w = 0; w < 8; ++w) {
        float t = qs1[w * 3] * cx + qs1[w * 3 + 1] * cy + qs1[w * 3 + 2] * cz;
        accu = fmaf(dot16u(base + w * 16, hk), t, accu);
      }
      S1c += accu;
    }

    float s = PWSIM_F * (PW0_F * (S0a + INV3_F * S0b) +
                         (INV3_F * PW1_F) * (INV3_F * S1a + INV3_F * S1b + INV6_F * S1c));
    s_out[p] = s;
  }

  // ------- value phase -------
  float v0[16];
#pragma unroll
  for (int w = 0; w < 16; ++w) v0[w] = 0.f;
  float v1[24];
#pragma unroll
  for (int w = 0; w < 24; ++w) v1[w] = 0.f;

#pragma unroll 1
  for (int u = 0; u < 16; ++u) {
    const float* base = W2Tv + (u * 16) * 16;
    float xu = myx[u];
#pragma unroll
    for (int w = 0; w < 16; ++w) v0[w] = fmaf(dot16u(base + w * 16, hv), xu, v0[w]);
  }
  {
    float aw[8];
#pragma unroll
    for (int w = 0; w < 8; ++w) aw[w] = 0.f;
#pragma unroll 1
    for (int u = 0; u < 16; ++u) {
      const float* base = W2Tv + (256 + u * 8) * 16;
      float xu = myx[u];
#pragma unroll
      for (int w = 0; w < 8; ++w) aw[w] = fmaf(dot16u(base + w * 16, hv), xu, aw[w]);
    }
#pragma unroll
    for (int w = 0; w < 8; ++w) {
      float t = INV3_F * aw[w];
      v1[w * 3 + 0] = fmaf(t, sh1[0], v1[w * 3 + 0]);
      v1[w * 3 + 1] = fmaf(t, sh1[1], v1[w * 3 + 1]);
      v1[w * 3 + 2] = fmaf(t, sh1[2], v1[w * 3 + 2]);
    }
  }
#pragma unroll 1
  for (int u = 0; u < 8; ++u) {
    const float* base = W2Tv + (384 + u * 8) * 16;
    float a0 = INV3_F * myx[16 + u * 3 + 0];
    float a1 = INV3_F * myx[16 + u * 3 + 1];
    float a2 = INV3_F * myx[16 + u * 3 + 2];
#pragma unroll
    for (int w = 0; w < 8; ++w) {
      float wk = dot16u(base + w * 16, hv);
      v1[w * 3 + 0] = fmaf(wk, a0, v1[w * 3 + 0]);
      v1[w * 3 + 1] = fmaf(wk, a1, v1[w * 3 + 1]);
      v1[w * 3 + 2] = fmaf(wk, a2, v1[w * 3 + 2]);
    }
  }
#pragma unroll 1
  for (int u = 0; u < 8; ++u) {
    const float* base = W2Tv + (448 + u * 16) * 16;
    float x1a = myx[16 + u * 3 + 0], x1b = myx[16 + u * 3 + 1], x1c = myx[16 + u * 3 + 2];
    float du = INV3_F * (x1a * sh1[0] + x1b * sh1[1] + x1c * sh1[2]);
#pragma unroll
    for (int w = 0; w < 16; ++w) v0[w] = fmaf(dot16u(base + w * 16, hv), du, v0[w]);
  }
#pragma unroll 1
  for (int u = 0; u < 8; ++u) {
    const float* base = W2Tv + (576 + u * 8) * 16;
    float x1a = myx[16 + u * 3 + 0], x1b = myx[16 + u * 3 + 1], x1c = myx[16 + u * 3 + 2];
    float cx = INV6_F * (x1b * sh1[2] - x1c * sh1[1]);
    float cy = INV6_F * (x1c * sh1[0] - x1a * sh1[2]);
    float cz = INV6_F * (x1a * sh1[1] - x1b * sh1[0]);
#pragma unroll
    for (int w = 0; w < 8; ++w) {
      float wk = dot16u(base + w * 16, hv);
      v1[w * 3 + 0] = fmaf(wk, cx, v1[w * 3 + 0]);
      v1[w * 3 + 1] = fmaf(wk, cy, v1[w * 3 + 1]);
      v1[w * 3 + 2] = fmaf(wk, cz, v1[w * 3 + 2]);
    }
  }

  float outv[40];
#pragma unroll
  for (int w = 0; w < 16; ++w) outv[w] = PW0_F * v0[w];
#pragma unroll
  for (int w = 0; w < 24; ++w) outv[16 + w] = PW1_F * v1[w];
  float4* st = reinterpret_cast<float4*>(staging + (size_t)p * 40);
#pragma unroll
  for (int q = 0; q < 10; ++q)
    st[q] = make_float4(outv[q * 4], outv[q * 4 + 1], outv[q * 4 + 2], outv[q * 4 + 3]);
}

// ---------- per-node softmax + gather ----------

__global__ void k_softmax(const float* __restrict__ s, const int* __restrict__ off,
                          float* __restrict__ coef, int N) {
  int gid = blockIdx.x * blockDim.x + threadIdx.x;
  int wid = gid >> 6;
  int lane = threadIdx.x & 63;
  if (wid >= N) return;
  int lo = off[wid], hi = off[wid + 1];
  float m = -1e30f;
  for (int p = lo + lane; p < hi; p += 64) m = fmaxf(m, s[p]);
#pragma unroll
  for (int d = 32; d; d >>= 1) m = fmaxf(m, __shfl_xor(m, d));
  float sum = 0.f;
  for (int p = lo + lane; p < hi; p += 64) sum += __expf(s[p] - m);
#pragma unroll
  for (int d = 32; d; d >>= 1) sum += __shfl_xor(sum, d);
  float inv = 1.0f / sum;
  for (int p = lo + lane; p < hi; p += 64)
    coef[p] = sqrtf(__expf(s[p] - m) * inv);
}

__global__ void k_gather(const float* __restrict__ staging, const float* __restrict__ coef,
                         const int* __restrict__ off, float* __restrict__ out, int N) {
  int gid = blockIdx.x * blockDim.x + threadIdx.x;
  int wid = gid >> 6;
  int lane = threadIdx.x & 63;
  if (wid >= N) return;
  int lo = off[wid], hi = off[wid + 1];
  float acc = 0.f;
  if (lane < 40) {
    for (int p = lo; p < hi; ++p)
      acc = fmaf(coef[p], staging[(size_t)p * 40 + lane], acc);
    out[(size_t)wid * 40 + lane] = acc;
  }
}

// ---------- fallback (atomic) path kernels — round-1 pipeline ----------

__global__ __launch_bounds__(TPB) void k_edge_key(
    const float* __restrict__ x, const float* __restrict__ pos,
    const int* __restrict__ esrc, const int* __restrict__ edst,
    const float* __restrict__ W1, const float* __restrict__ W2T,
    const float* __restrict__ qs0g, const float* __restrict__ qs1g,
    float* __restrict__ s_out, unsigned int* __restrict__ smax_enc, int E) {
  __shared__ float xs[TPB * 41];
  int e = blockIdx.x * TPB + threadIdx.x;
  if (e >= E) return;
  int src = esrc[e], dst = edst[e];
  float* myx = &xs[threadIdx.x * 41];
  const float4* xrow = reinterpret_cast<const float4*>(x + (size_t)src * 40);
#pragma unroll
  for (int q = 0; q < 10; ++q) {
    float4 v = xrow[q];
    myx[q * 4 + 0] = v.x; myx[q * 4 + 1] = v.y; myx[q * 4 + 2] = v.z; myx[q * 4 + 3] = v.w;
  }
  float sh1[3], h[16];
  compute_h(pos, W1, src, dst, sh1, h);
  float qs0[16];
  {
    const float4* p = reinterpret_cast<const float4*>(qs0g + (size_t)dst * 16);
#pragma unroll
    for (int q = 0; q < 4; ++q) {
      float4 v = p[q];
      qs0[q * 4 + 0] = v.x; qs0[q * 4 + 1] = v.y; qs0[q * 4 + 2] = v.z; qs0[q * 4 + 3] = v.w;
    }
  }
  float qs1[24];
  {
    const float4* p = reinterpret_cast<const float4*>(qs1g + (size_t)dst * 24);
#pragma unroll
    for (int q = 0; q < 6; ++q) {
      float4 v = p[q];
      qs1[q * 4 + 0] = v.x; qs1[q * 4 + 1] = v.y; qs1[q * 4 + 2] = v.z; qs1[q * 4 + 3] = v.w;
    }
  }
  float qsh[8];
#pragma unroll
  for (int w = 0; w < 8; ++w)
    qsh[w] = qs1[w * 3] * sh1[0] + qs1[w * 3 + 1] * sh1[1] + qs1[w * 3 + 2] * sh1[2];
  float S0a = 0.f, S0b = 0.f, S1a = 0.f, S1b = 0.f, S1c = 0.f;
#pragma unroll 1
  for (int u = 0; u < 16; ++u) {
    const float* base = W2T + (u * 16) * 16;
    float accu = 0.f;
#pragma unroll
    for (int w = 0; w < 16; ++w) accu = fmaf(dot16u(base + w * 16, h), qs0[w], accu);
    S0a = fmaf(accu, myx[u], S0a);
  }
#pragma unroll 1
  for (int u = 0; u < 16; ++u) {
    const float* base = W2T + (256 + u * 8) * 16;
    float accu = 0.f;
#pragma unroll
    for (int w = 0; w < 8; ++w) accu = fmaf(dot16u(base + w * 16, h), qsh[w], accu);
    S1a = fmaf(accu, myx[u], S1a);
  }
#pragma unroll 1
  for (int u = 0; u < 8; ++u) {
    const float* base = W2T + (384 + u * 8) * 16;
    float x1a = myx[16 + u * 3 + 0], x1b = myx[16 + u * 3 + 1], x1c = myx[16 + u * 3 + 2];
    float accu = 0.f;
#pragma unroll
    for (int w = 0; w < 8; ++w) {
      float t = qs1[w * 3] * x1a + qs1[w * 3 + 1] * x1b + qs1[w * 3 + 2] * x1c;
      accu = fmaf(dot16u(base + w * 16, h), t, accu);
    }
    S1b += accu;
  }
#pragma unroll 1
  for (int u = 0; u < 8; ++u) {
    const float* base = W2T + (448 + u * 16) * 16;
    float x1a = myx[16 + u * 3 + 0], x1b = myx[16 + u * 3 + 1], x1c = myx[16 + u * 3 + 2];
    float du = x1a * sh1[0] + x1b * sh1[1] + x1c * sh1[2];
    float accu = 0.f;
#pragma unroll
    for (int w = 0; w < 16; ++w) accu = fmaf(dot16u(base + w * 16, h), qs0[w], accu);
    S0b = fmaf(accu, du, S0b);
  }
#pragma unroll 1
  for (int u = 0; u < 8; ++u) {
    const float* base = W2T + (576 + u * 8) * 16;
    float x1a = myx[16 + u * 3 + 0], x1b = myx[16 + u * 3 + 1], x1c = myx[16 + u * 3 + 2];
    float cx = x1b * sh1[2] - x1c * sh1[1];
    float cy = x1c * sh1[0] - x1a * sh1[2];
    float cz = x1a * sh1[1] - x1b * sh1[0];
    float accu = 0.f;
#pragma unroll
    for (int w = 0; w < 8; ++w) {
      float t = qs1[w * 3] * cx + qs1[w * 3 + 1] * cy + qs1[w * 3 + 2] * cz;
      accu = fmaf(dot16u(base + w * 16, h), t, accu);
    }
    S1c += accu;
  }
  float s = PWSIM_F * (PW0_F * (S0a + INV3_F * S0b) +
                       (INV3_F * PW1_F) * (INV3_F * S1a + INV3_F * S1b + INV6_F * S1c));
  s_out[e] = s;
  atomicMax(&smax_enc[dst], fkey(s));
}

__global__ void k_denom(const float* __restrict__ s_in, const int* __restrict__ edst,
                        const unsigned int* __restrict__ smax_enc,
                        float* __restrict__ denom, int E) {
  int e = blockIdx.x * blockDim.x + threadIdx.x;
  if (e >= E) return;
  int dst = edst[e];
  float mx = fdec(smax_enc[dst]);
  atomAddF(&denom[dst], __expf(s_in[e] - mx));
}

__global__ __launch_bounds__(TPB) void k_edge_val(
    const float* __restrict__ x, const float* __restrict__ pos,
    const int* __restrict__ esrc, const int* __restrict__ edst,
    const float* __restrict__ W1, const float* __restrict__ W2T,
    const float* __restrict__ s_in, const unsigned int* __restrict__ smax_enc,
    const float* __restrict__ denom, float* __restrict__ out, int E) {
  __shared__ float xs[TPB * 41];
  int e = blockIdx.x * TPB + threadIdx.x;
  if (e >= E) return;
  int src = esrc[e], dst = edst[e];
  float* myx = &xs[threadIdx.x * 41];
  const float4* xrow = reinterpret_cast<const float4*>(x + (size_t)src * 40);
#pragma unroll
  for (int q = 0; q < 10; ++q) {
    float4 v = xrow[q];
    myx[q * 4 + 0] = v.x; myx[q * 4 + 1] = v.y; myx[q * 4 + 2] = v.z; myx[q * 4 + 3] = v.w;
  }
  float sh1[3], h[16];
  compute_h(pos, W1, src, dst, sh1, h);
  float v0[16];
#pragma unroll
  for (int w = 0; w < 16; ++w) v0[w] = 0.f;
  float v1[24];
#pragma unroll
  for (int w = 0; w < 24; ++w) v1[w] = 0.f;
#pragma unroll 1
  for (int u = 0; u < 16; ++u) {
    const float* base = W2T + (u * 16) * 16;
    float xu = myx[u];
#pragma unroll
    for (int w = 0; w < 16; ++w) v0[w] = fmaf(dot16u(base + w * 16, h), xu, v0[w]);
  }
  float aw[8];
#pragma unroll
  for (int w = 0; w < 8; ++w) aw[w] = 0.f;
#pragma unroll 1
  for (int u = 0; u < 16; ++u) {
    const float* base = W2T + (256 + u * 8) * 16;
    float xu = myx[u];
#pragma unroll
    for (int w = 0; w < 8; ++w) aw[w] = fmaf(dot16u(base + w * 16, h), xu, aw[w]);
  }
#pragma unroll
  for (int w = 0; w < 8; ++w) {
    float t = INV3_F * aw[w];
    v1[w * 3 + 0] = fmaf(t, sh1[0], v1[w * 3 + 0]);
    v1[w * 3 + 1] = fmaf(t, sh1[1], v1[w * 3 + 1]);
    v1[w * 3 + 2] = fmaf(t, sh1[2], v1[w * 3 + 2]);
  }
#pragma unroll 1
  for (int u = 0; u < 8; ++u) {
    const float* base = W2T + (384 + u * 8) * 16;
    float a0 = INV3_F * myx[16 + u * 3 + 0];
    float a1 = INV3_F * myx[16 + u * 3 + 1];
    float a2 = INV3_F * myx[16 + u * 3 + 2];
#pragma unroll
    for (int w = 0; w < 8; ++w) {
      float wk = dot16u(base + w * 16, h);
      v1[w * 3 + 0] = fmaf(wk, a0, v1[w * 3 + 0]);
      v1[w * 3 + 1] = fmaf(wk, a1, v1[w * 3 + 1]);
      v1[w * 3 + 2] = fmaf(wk, a2, v1[w * 3 + 2]);
    }
  }
#pragma unroll 1
  for (int u = 0; u < 8; ++u) {
    const float* base = W2T + (448 + u * 16) * 16;
    float x1a = myx[16 + u * 3 + 0], x1b = myx[16 + u * 3 + 1], x1c = myx[16 + u * 3 + 2];
    float du = INV3_F * (x1a * sh1[0] + x1b * sh1[1] + x1c * sh1[2]);
#pragma unroll
    for (int w = 0; w < 16; ++w) v0[w] = fmaf(dot16u(base + w * 16, h), du, v0[w]);
  }
#pragma unroll 1
  for (int u = 0; u < 8; ++u) {
    const float* base = W2T + (576 + u * 8) * 16;
    float x1a = myx[16 + u * 3 + 0], x1b = myx[16 + u * 3 + 1], x1c = myx[16 + u * 3 + 2];
    float cx = INV6_F * (x1b * sh1[2] - x1c * sh1[1]);
    float cy = INV6_F * (x1c * sh1[0] - x1a * sh1[2]);
    float cz = INV6_F * (x1a * sh1[1] - x1b * sh1[0]);
#pragma unroll
    for (int w = 0; w < 8; ++w) {
      float wk = dot16u(base + w * 16, h);
      v1[w * 3 + 0] = fmaf(wk, cx, v1[w * 3 + 0]);
      v1[w * 3 + 1] = fmaf(wk, cy, v1[w * 3 + 1]);
      v1[w * 3 + 2] = fmaf(wk, cz, v1[w * 3 + 2]);
    }
  }
  float mx = fdec(smax_enc[dst]);
  float ex = __expf(s_in[e] - mx);
  float coef = sqrtf(__fdividef(ex, denom[dst]));
  float* op = out + (size_t)dst * 40;
#pragma unroll
  for (int w = 0; w < 16; ++w) atomAddF(op + w, coef * PW0_F * v0[w]);
#pragma unroll
  for (int w = 0; w < 24; ++w) atomAddF(op + 16 + w, coef * PW1_F * v1[w]);
}

// ---------- host launcher ----------

extern "C" void kernel_launch(void* const* d_in, const int* in_sizes, int n_in,
                              void* d_out, int out_size, void* d_ws, size_t ws_size,
                              hipStream_t stream) {
  const float* x   = (const float*)d_in[0];
  const float* pos = (const float*)d_in[1];
  const int* esrc  = (const int*)d_in[2];
  const int* edst  = (const int*)d_in[3];
  const float* wk1 = (const float*)d_in[4];
  const float* wk2 = (const float*)d_in[5];
  const float* wv1 = (const float*)d_in[6];
  const float* wv2 = (const float*)d_in[7];
  const float* wq0 = (const float*)d_in[8];
  const float* wq1 = (const float*)d_in[9];
  const float* ws0 = (const float*)d_in[10];
  const float* ws1 = (const float*)d_in[11];

  int E = in_sizes[2];
  int N = in_sizes[0] / 40;

  float* ws = (float*)d_ws;
  float* W2Tk = ws;                        // 10240
  float* W2Tv = ws + 10240;                // 10240
  float* C0   = ws + 20480;                // 256
  float* C1   = ws + 20736;                // 64
  float* qs0g = ws + 20800;                // N*16
  float* qs1g = qs0g + (size_t)N * 16;     // N*24
  float* s_ws = qs1g + (size_t)N * 24;     // E

  // staging-path layout (after s_ws)
  float* coef = s_ws + (size_t)E;                       // E
  int* cnt    = (int*)(coef + (size_t)E);               // N
  int* off    = cnt + (size_t)N;                        // N+1
  int* cursor = off + (size_t)N + 1;                    // N
  int* perm   = cursor + (size_t)N;                     // E
  float* staging = (float*)(perm + (size_t)E);          // E*40

  size_t need_full = ((size_t)20800 + (size_t)N * 40 + (size_t)E * 2 +
                      (size_t)N * 3 + 1 + (size_t)E + (size_t)E * 40) * 4;

  k_prep<<<(20800 + 255) / 256, 256, 0, stream>>>(wk2, wv2, wq0, wq1, ws0, ws1,
                                                  W2Tk, W2Tv, C0, C1);
  k_node<<<(N + 255) / 256, 256, 0, stream>>>(x, C0, C1, qs0g, qs1g, N);

  if (ws_size >= need_full) {
    // ---- CSR + staging path (no output atomics) ----
    hipMemsetAsync(cnt, 0, sizeof(int) * (size_t)N, stream);
    k_hist<<<(E + 255) / 256, 256, 0, stream>>>(edst, cnt, E);
    k_scan<<<1, 1024, 0, stream>>>(cnt, off, cursor, N);
    k_place<<<(E + 255) / 256, 256, 0, stream>>>(edst, cursor, perm, E);
    k_edge_fused<<<(E + TPB - 1) / TPB, TPB, 0, stream>>>(
        x, pos, esrc, edst, perm, wk1, W2Tk, wv1, W2Tv, qs0g, qs1g,
        s_ws, staging, E);
    k_softmax<<<((N * 64) + 255) / 256, 256, 0, stream>>>(s_ws, off, coef, N);
    k_gather<<<((N * 64) + 255) / 256, 256, 0, stream>>>(staging, coef, off,
                                                         (float*)d_out, N);
  } else {
    // ---- fallback: round-1 atomic path ----
    unsigned int* smax_enc = (unsigned int*)(s_ws + (size_t)E);
    float* denom = (float*)(smax_enc + (size_t)N);
    hipMemsetAsync(d_out, 0, sizeof(float) * (size_t)out_size, stream);
    hipMemsetAsync(smax_enc, 0, sizeof(unsigned int) * (size_t)N, stream);
    hipMemsetAsync(denom, 0, sizeof(float) * (size_t)N, stream);
    k_edge_key<<<(E + TPB - 1) / TPB, TPB, 0, stream>>>(x, pos, esrc, edst, wk1, W2Tk,
                                                        qs0g, qs1g, s_ws, smax_enc, E);
    k_denom<<<(E + 255) / 256, 256, 0, stream>>>(s_ws, edst, smax_enc, denom, E);
    k_edge_val<<<(E + TPB - 1) / TPB, TPB, 0, stream>>>(x, pos, esrc, edst, wv1, W2Tv,
                                                        s_ws, smax_enc, denom,
                                                        (float*)d_out, E);
  }
}